// Round 4
// baseline (116.243 us; speedup 1.0000x reference)
//
#include <hip/hip_runtime.h>

// InterpolationBlock1D_Lin, two-phase:
//   K1 (gather): n12[e] = (nodal[conn[cell_id[e]].x-1], nodal[conn[...].y-1])  — 36 MB, latency-tolerant
//   K2 (stream): out[e][k] = sf[e][0][k]*n12[e].x + sf[e][1][k]*n12[e].y       — 400 MB pure stream
// Decoupling keeps random 4-8B gathers out of the HBM burst stream.

typedef float f32x4 __attribute__((ext_vector_type(4)));

__global__ __launch_bounds__(256) void gather_nodes_kernel(
    const int*   __restrict__ cell_id,   // [N_EVAL]
    const float* __restrict__ nodal,     // [N_NODES]
    const int2*  __restrict__ conn,      // [N_CELLS][2], 1-based
    float2*      __restrict__ n12,       // [N_EVAL] workspace
    int n_eval)
{
    int e = blockIdx.x * blockDim.x + threadIdx.x;
    if (e >= n_eval) return;
    int c = cell_id[e];
    int2 nn = conn[c];
    float2 r;
    r.x = nodal[nn.x - 1];
    r.y = nodal[nn.y - 1];
    n12[e] = r;
}

__global__ __launch_bounds__(256) void interp_stream_kernel(
    const float2* __restrict__ n12,      // [N_EVAL]
    const f32x4*  __restrict__ sf,       // [N_EVAL][2][16] -> 8 f32x4/eval
    f32x4*        __restrict__ out,      // [N_EVAL][16]    -> 4 f32x4/eval
    int n_out4)
{
    int i = blockIdx.x * blockDim.x + threadIdx.x;
    if (i >= n_out4) return;
    int e = i >> 2;
    int j = i & 3;

    float2 n = n12[e];                       // 4 lanes broadcast same 8B
    const f32x4* s = sf + ((size_t)e * 8 + j);
    f32x4 a = __builtin_nontemporal_load(s);     // sf[e][0][4j..]
    f32x4 b = __builtin_nontemporal_load(s + 4); // sf[e][1][4j..]
    f32x4 r = a * n.x + b * n.y;
    __builtin_nontemporal_store(r, out + i);
}

// Fallback (ws too small): fused single kernel, round-3 version.
__global__ __launch_bounds__(256) void interp_fused_kernel(
    const int*   __restrict__ cell_id,
    const float* __restrict__ nodal,
    const f32x4* __restrict__ sf,
    const int2*  __restrict__ conn,
    f32x4*       __restrict__ out,
    int n_out4)
{
    int i = blockIdx.x * blockDim.x + threadIdx.x;
    if (i >= n_out4) return;
    int e = i >> 2;
    int j = i & 3;
    int c = cell_id[e];
    int2 nn = conn[c];
    float n1 = nodal[nn.x - 1];
    float n2 = nodal[nn.y - 1];
    const f32x4* s = sf + ((size_t)e * 8 + j);
    f32x4 a = __builtin_nontemporal_load(s);
    f32x4 b = __builtin_nontemporal_load(s + 4);
    f32x4 r = a * n1 + b * n2;
    __builtin_nontemporal_store(r, out + i);
}

extern "C" void kernel_launch(void* const* d_in, const int* in_sizes, int n_in,
                              void* d_out, int out_size, void* d_ws, size_t ws_size,
                              hipStream_t stream) {
    // Input order: x, cell_id, nodal_values, shape_functions, connectivity
    const int*   cell_id = (const int*)d_in[1];
    const float* nodal   = (const float*)d_in[2];
    const f32x4* sf      = (const f32x4*)d_in[3];
    const int2*  conn    = (const int2*)d_in[4];
    f32x4*       out     = (f32x4*)d_out;

    int n_eval = in_sizes[1];
    int n_out4 = n_eval * 4;
    int block = 256;

    size_t need = (size_t)n_eval * sizeof(float2);
    if (ws_size >= need) {
        float2* n12 = (float2*)d_ws;
        gather_nodes_kernel<<<(n_eval + block - 1) / block, block, 0, stream>>>(
            cell_id, nodal, conn, n12, n_eval);
        interp_stream_kernel<<<(n_out4 + block - 1) / block, block, 0, stream>>>(
            n12, sf, out, n_out4);
    } else {
        interp_fused_kernel<<<(n_out4 + block - 1) / block, block, 0, stream>>>(
            cell_id, nodal, sf, conn, out, n_out4);
    }
}